// Round 6
// baseline (372.819 us; speedup 1.0000x reference)
//
#include <hip/hip_runtime.h>
#include <hip/hip_bf16.h>

// ---------- problem constants ----------
#define N_NODES 50000
#define N_EDGES 800000
#define C_DIM   256      // IN_C == HID_C
#define OUT_C   128
#define N_GRAPHS 256

typedef __bf16         bf16x8  __attribute__((ext_vector_type(8)));
typedef float          f32x4   __attribute__((ext_vector_type(4)));

typedef __attribute__((address_space(1))) const unsigned int gu32;
typedef __attribute__((address_space(3))) unsigned int lu32;

#if __has_builtin(__builtin_amdgcn_sched_barrier)
#define SCHED_FENCE() __builtin_amdgcn_sched_barrier(0)
#else
#define SCHED_FENCE() ((void)0)
#endif

__device__ __forceinline__ float us2f(unsigned short u) {
    unsigned int x = ((unsigned int)u) << 16;
    return __builtin_bit_cast(float, x);
}
__device__ __forceinline__ unsigned short f2bf(float f) {
    unsigned int u = __builtin_bit_cast(unsigned int, f);
    u += 0x7fffu + ((u >> 16) & 1u);   // RNE
    return (unsigned short)(u >> 16);
}

__device__ __forceinline__ int lower_bound_i(const int* __restrict__ a, int n, int v) {
    int lo = 0, hi = n;
    while (lo < hi) {
        int mid = (lo + hi) >> 1;
        if (a[mid] < v) lo = mid + 1; else hi = mid;
    }
    return lo;
}

// ---------- K1: merged preprocess (slimmed: 3449 blocks vs 12760) ----------
// blocks [0,3125): convert x f32->bf16 (16 elems/thread, coalesced)
// blocks [3125,3189): LDS-tiled transpose+convert of the 4 weights
// blocks [3189,3385): CSR row_ptr/graph_ptr/inv_deg
// blocks [3385,3449): zero gsum (256x256 f32)
__global__ void preprocess(const float* __restrict__ x, unsigned short* __restrict__ xb,
                           const float* __restrict__ W0, const float* __restrict__ W1,
                           const float* __restrict__ W2, const float* __restrict__ W3,
                           unsigned short* __restrict__ D0, unsigned short* __restrict__ D1,
                           unsigned short* __restrict__ D2, unsigned short* __restrict__ D3,
                           const int* __restrict__ dst, const int* __restrict__ batch,
                           int* __restrict__ row_ptr, int* __restrict__ graph_ptr,
                           float* __restrict__ inv_deg, float* __restrict__ gsum) {
    __shared__ float tile[64][65];
    int b = blockIdx.x;
    int t = threadIdx.x;
    if (b < 3125) {
        int base = b * 1024 + t;             // float4-group index
#pragma unroll
        for (int j = 0; j < 4; ++j) {
            int i = base + j * 256;          // < 3.2M
            float4 v = *(const float4*)(x + ((size_t)i << 2));
            ushort4 o;
            o.x = f2bf(v.x); o.y = f2bf(v.y); o.z = f2bf(v.z); o.w = f2bf(v.w);
            *(ushort4*)(xb + ((size_t)i << 2)) = o;
        }
    } else if (b < 3189) {
        int b2 = b - 3125;                   // 0..63: 4 matrices x 16 tiles
        const float* S; unsigned short* D;
        switch (b2 >> 4) {
            case 0: S = W0; D = D0; break;
            case 1: S = W1; D = D1; break;
            case 2: S = W2; D = D2; break;
            default: S = W3; D = D3; break;
        }
        int tl = b2 & 15;
        int kt = (tl >> 2) * 64, nt = (tl & 3) * 64;
#pragma unroll
        for (int j = 0; j < 16; ++j) {       // coalesced read of S[kt.., nt..]
            int idx = t + j * 256;
            int r = idx >> 6, c = idx & 63;
            tile[r][c] = S[(size_t)(kt + r) * 256 + nt + c];
        }
        __syncthreads();
#pragma unroll
        for (int j = 0; j < 16; ++j) {       // coalesced write of D[nt.., kt..]
            int idx = t + j * 256;
            int r = idx >> 6, c = idx & 63;
            D[(size_t)(nt + r) * 256 + kt + c] = f2bf(tile[c][r]);
        }
    } else if (b < 3385) {
        int i = (b - 3189) * 256 + t;
        if (i <= N_NODES) {
            int lb = lower_bound_i(dst, N_EDGES, i);
            row_ptr[i] = lb;
            if (i < N_NODES) {
                int ub = lower_bound_i(dst, N_EDGES, i + 1);
                int cnt = ub - lb;
                inv_deg[i] = (cnt > 0) ? (1.0f / (float)cnt) : 0.0f;
            }
        }
        if (i <= N_GRAPHS) graph_ptr[i] = lower_bound_i(batch, N_NODES, i);
    } else {
        int i = (b - 3385) * 256 + t;        // 0..16383 float4 slots
        f32x4 z = {0.f, 0.f, 0.f, 0.f};
        ((f32x4*)gsum)[i] = z;
    }
}

// ---------- K2: mean aggregation (round-0 verbatim — 57 µs structural ceiling) ----------
// One wave per node, scalar-base gathers, 16-deep fenced bursts. Do NOT fuse
// with GEMM (r1: −24%) or into a coop mega-kernel (r4: −3.5x) — gather needs
// max independent-wave concurrency and its own launch shape.
__global__ void aggregate(const unsigned short* __restrict__ X,
                          const int* __restrict__ src,
                          const int* __restrict__ row_ptr,
                          const float* __restrict__ inv_deg,
                          unsigned short* __restrict__ out) {
    int gw   = (blockIdx.x * blockDim.x + threadIdx.x) >> 6;
    int lane = threadIdx.x & 63;
    if (gw >= N_NODES) return;
    int e0 = row_ptr[gw], e1 = row_ptr[gw + 1];
    const int lo = lane << 2;
    float a0 = 0.f, a1 = 0.f, a2 = 0.f, a3 = 0.f;
    int e = e0;

    for (; e + 16 <= e1; e += 16) {
        ushort4 v[16];
#pragma unroll
        for (int j = 0; j < 16; ++j) {
            int s = __builtin_amdgcn_readfirstlane(src[e + j]);
            v[j] = *(const ushort4*)(X + ((size_t)s << 8) + lo);
        }
        SCHED_FENCE();
#pragma unroll
        for (int j = 0; j < 16; ++j) {
            a0 += us2f(v[j].x); a1 += us2f(v[j].y);
            a2 += us2f(v[j].z); a3 += us2f(v[j].w);
        }
    }
    int rem = e1 - e;
    if (rem > 0) {
        int cl = e1 - 1;
        ushort4 v[16]; float w[16];
#pragma unroll
        for (int j = 0; j < 16; ++j) {
            int ej = e + j;
            int ec = ej < cl ? ej : cl;
            w[j] = (ej < e1) ? 1.0f : 0.0f;
            int s = __builtin_amdgcn_readfirstlane(src[ec]);
            v[j] = *(const ushort4*)(X + ((size_t)s << 8) + lo);
        }
        SCHED_FENCE();
#pragma unroll
        for (int j = 0; j < 16; ++j) {
            a0 = fmaf(us2f(v[j].x), w[j], a0);
            a1 = fmaf(us2f(v[j].y), w[j], a1);
            a2 = fmaf(us2f(v[j].z), w[j], a2);
            a3 = fmaf(us2f(v[j].w), w[j], a3);
        }
    }

    float sc = inv_deg[gw];
    ushort4 o;
    o.x = f2bf(a0 * sc); o.y = f2bf(a1 * sc); o.z = f2bf(a2 * sc); o.w = f2bf(a3 * sc);
    *(ushort4*)(out + ((size_t)gw << 8) + lo) = o;
}

// ---------- K3: fused SAGE GEMM (round-0 main loop — verified 32 µs optimum) ----------
// 128-row strip x FULL N=256; 512 thr = 8 waves (2m x 4n), 4x4 MFMA 16x16x32
// per wave, BK=64. Main loop is the measured best across 7 restructure
// attempts (prior r7/r8/r10/r11; this session r1/r3/r5) — do not touch.
// NEW: do_pool epilogue folds the p-weighted graph pooling into the C-write
// (LDS per-graph partials -> 1 global atomicAdd per (graph,chan) per block),
// deleting pool_final's 25.6 MB h2 re-read.
__global__ __launch_bounds__(512, 2)
void gemm_fused(const unsigned short* __restrict__ A1,
                const unsigned short* __restrict__ A2,
                const unsigned short* __restrict__ B1t,
                const unsigned short* __restrict__ B2t,
                const float* __restrict__ bias,
                unsigned short* __restrict__ C,
                int M, int do_relu,
                const float* __restrict__ p,
                const int* __restrict__ batch,
                float* __restrict__ gsum, int do_pool) {
    __shared__ __align__(16) unsigned short As[8192];   // 128 rows x 8 chunks x 8
    __shared__ __align__(16) unsigned short Bs[16384];  // 256 rows x 8 chunks x 8
    __shared__ float pool_lds[8][256];                  // 8 graph slots (block spans <=3)

    const int t    = threadIdx.x;
    const int m0   = blockIdx.x * 128;
    const int lane = t & 63, wid = t >> 6;
    const int wm   = (wid >> 2) * 64;       // {0,64}
    const int wn   = (wid & 3) * 64;        // {0,64,128,192}
    const int lrow = lane & 15;
    const int kq   = lane >> 4;             // 0..3

    if (do_pool) {
        for (int i = t; i < 2048; i += 512) ((float*)pool_lds)[i] = 0.f;
        // no barrier needed yet: first pool_lds use is after several __syncthreads
    }

    const f32x4 zero4 = {0.f, 0.f, 0.f, 0.f};
    f32x4 acc[4][4];
#pragma unroll
    for (int i = 0; i < 4; ++i)
#pragma unroll
        for (int j = 0; j < 4; ++j) acc[i][j] = zero4;

    for (int it = 0; it < 8; ++it) {        // K = 512 virtual (2 x 256), BK = 64
        const unsigned short* __restrict__ Ab = (it < 4) ? A1 : A2;
        const unsigned short* __restrict__ Bb = (it < 4) ? B1t : B2t;
        int ko = (it * 64) & 255;

#pragma unroll
        for (int i = 0; i < 2; ++i) {
            int q   = t + i * 512;          // 0..1023
            int row = q >> 3;
            int kb  = (q & 7) ^ (row & 7);
            const unsigned short* ga = Ab + (size_t)(m0 + row) * 256 + ko + kb * 8;
            __builtin_amdgcn_global_load_lds((gu32*)ga, (lu32*)(As + q * 8), 16, 0, 0);
        }
#pragma unroll
        for (int i = 0; i < 4; ++i) {
            int q   = t + i * 512;          // 0..2047
            int row = q >> 3;
            int kb  = (q & 7) ^ (row & 7);
            const unsigned short* gb = Bb + (size_t)row * 256 + ko + kb * 8;
            __builtin_amdgcn_global_load_lds((gu32*)gb, (lu32*)(Bs + q * 8), 16, 0, 0);
        }
        __syncthreads();

#pragma unroll
        for (int s = 0; s < 2; ++s) {       // two 32-k MFMA steps per BK=64
            int kqp = s * 4 + kq;
            bf16x8 af[4], bfr[4];
#pragma unroll
            for (int mi = 0; mi < 4; ++mi) {
                int r = wm + mi * 16 + lrow;
                int slot = r * 8 + (kqp ^ (lrow & 7));
                uint4 u = *(const uint4*)(As + slot * 8);
                af[mi] = __builtin_bit_cast(bf16x8, u);
            }
#pragma unroll
            for (int ni = 0; ni < 4; ++ni) {
                int r = wn + ni * 16 + lrow;
                int slot = r * 8 + (kqp ^ (lrow & 7));
                uint4 u = *(const uint4*)(Bs + slot * 8);
                bfr[ni] = __builtin_bit_cast(bf16x8, u);
            }
#pragma unroll
            for (int mi = 0; mi < 4; ++mi)
#pragma unroll
                for (int ni = 0; ni < 4; ++ni)
                    acc[mi][ni] = __builtin_amdgcn_mfma_f32_16x16x32_bf16(
                        af[mi], bfr[ni], acc[mi][ni], 0, 0, 0);
        }
        __syncthreads();
    }

    // epilogue: D mapping col = lane&15, row = (lane>>4)*4 + reg
    const int rbase = (lane >> 4) * 4;
    const int gfirst = do_pool ? batch[m0] : 0;
    float bv[4];
#pragma unroll
    for (int ni = 0; ni < 4; ++ni) bv[ni] = bias[wn + ni * 16 + lrow];

#pragma unroll
    for (int mi = 0; mi < 4; ++mi) {
#pragma unroll
        for (int r = 0; r < 4; ++r) {
            int m = m0 + wm + mi * 16 + rbase + r;
            if (m < M) {
                float pwv = 0.f; int slot = 0;
                if (do_pool) {
                    pwv  = p[m];
                    slot = (batch[m] - gfirst) & 7;
                }
#pragma unroll
                for (int ni = 0; ni < 4; ++ni) {
                    int n = wn + ni * 16 + lrow;
                    float v = acc[mi][ni][r] + bv[ni];
                    if (do_relu) v = fmaxf(v, 0.f);
                    C[(size_t)m * 256 + n] = f2bf(v);
                    if (do_pool) atomicAdd(&pool_lds[slot][n], pwv * v);
                }
            }
        }
    }

    if (do_pool) {
        __syncthreads();
        for (int i = t; i < 2048; i += 512) {
            int slot = i >> 8, n = i & 255;
            float v2 = ((float*)pool_lds)[i];
            int g = gfirst + slot;
            if (v2 != 0.f && g < N_GRAPHS)
                atomicAdd(&gsum[g * 256 + n], v2);
        }
    }
}

// ---------- K4: slim finale — root gather + gsum/cnt + final linear ----------
// Pooling sums now come from gemm2's epilogue (gsum). Per graph: 1 KB reads
// + 256 KB L2-resident Wlin. 256 blocks x 128 thr.
__global__ void pool_final(const unsigned short* __restrict__ h2,
                           const int* __restrict__ graph_ptr,
                           const int* __restrict__ root_ptr,
                           const float* __restrict__ gsum,
                           const float* __restrict__ Wlin,
                           const float* __restrict__ blin,
                           float* __restrict__ out) {
    __shared__ float fl[512];
    int g = blockIdx.x;
    int t = threadIdx.x;        // 128 threads
    int s = graph_ptr[g], e = graph_ptr[g + 1];
    float icnt = 1.0f / fmaxf((float)(e - s), 1.0f);
    int root = root_ptr[g];
#pragma unroll
    for (int c = t; c < 256; c += 128) {
        fl[c]       = us2f(h2[(size_t)root * 256 + c]);
        fl[256 + c] = gsum[g * 256 + c] * icnt;
    }
    __syncthreads();

    int o = t;
    float s0 = 0.f, s1 = 0.f, s2 = 0.f, s3 = 0.f;
    for (int k = 0; k < 512; k += 4) {
        s0 = fmaf(fl[k + 0], Wlin[(k + 0) * 128 + o], s0);
        s1 = fmaf(fl[k + 1], Wlin[(k + 1) * 128 + o], s1);
        s2 = fmaf(fl[k + 2], Wlin[(k + 2) * 128 + o], s2);
        s3 = fmaf(fl[k + 3], Wlin[(k + 3) * 128 + o], s3);
    }
    out[(size_t)g * 128 + o] = blin[o] + ((s0 + s1) + (s2 + s3));
}

extern "C" void kernel_launch(void* const* d_in, const int* in_sizes, int n_in,
                              void* d_out, int out_size, void* d_ws, size_t ws_size,
                              hipStream_t stream) {
    const float* x        = (const float*)d_in[0];
    const int*   src      = (const int*)d_in[1];
    const int*   dst      = (const int*)d_in[2];
    const float* p        = (const float*)d_in[3];
    const int*   batch    = (const int*)d_in[4];
    const int*   root_ptr = (const int*)d_in[5];
    // d_in[6] = num_graphs (256, hard-coded)
    const float* Wl1  = (const float*)d_in[7];
    const float* Wr1  = (const float*)d_in[8];
    const float* b1   = (const float*)d_in[9];
    const float* Wl2  = (const float*)d_in[10];
    const float* Wr2  = (const float*)d_in[11];
    const float* b2   = (const float*)d_in[12];
    const float* Wlin = (const float*)d_in[13];
    const float* blin = (const float*)d_in[14];
    float* out = (float*)d_out;

    // workspace layout (256B aligned slabs)
    size_t off = 0;
    char* base = (char*)d_ws;
    auto alloc = [&](size_t bytes) -> void* {
        void* q = base + off;
        off += (bytes + 255) & ~(size_t)255;
        return q;
    };
    int*            row_ptr   = (int*)  alloc((N_NODES + 1) * sizeof(int));
    int*            graph_ptr = (int*)  alloc((N_GRAPHS + 1) * sizeof(int));
    float*          inv_deg   = (float*)alloc(N_NODES * sizeof(float));
    float*          gsum      = (float*)alloc((size_t)N_GRAPHS * 256 * sizeof(float));
    unsigned short* Wl1t = (unsigned short*)alloc(256 * 256 * 2);
    unsigned short* Wr1t = (unsigned short*)alloc(256 * 256 * 2);
    unsigned short* Wl2t = (unsigned short*)alloc(256 * 256 * 2);
    unsigned short* Wr2t = (unsigned short*)alloc(256 * 256 * 2);
    unsigned short* xb   = (unsigned short*)alloc((size_t)N_NODES * 256 * 2);
    unsigned short* aggb = (unsigned short*)alloc((size_t)N_NODES * 256 * 2);
    unsigned short* h1   = (unsigned short*)alloc((size_t)N_NODES * 256 * 2);
    unsigned short* h2   = (unsigned short*)alloc((size_t)N_NODES * 256 * 2);
    (void)ws_size; (void)n_in; (void)in_sizes; (void)out_size;

    preprocess<<<3449, 256, 0, stream>>>(x, xb, Wl1, Wr1, Wl2, Wr2,
                                         Wl1t, Wr1t, Wl2t, Wr2t,
                                         dst, batch, row_ptr, graph_ptr, inv_deg,
                                         gsum);

    dim3 ggrid((N_NODES + 127) / 128);   // 391 blocks

    // conv1: h1 = relu(agg(x)@Wl1 + x@Wr1 + b1)
    aggregate<<<N_NODES / 4, 256, 0, stream>>>(xb, src, row_ptr, inv_deg, aggb);
    gemm_fused<<<ggrid, 512, 0, stream>>>(aggb, xb, Wl1t, Wr1t, b1, h1, N_NODES, 1,
                                          p, batch, gsum, 0);

    // conv2: h2 = agg(h1)@Wl2 + h1@Wr2 + b2  (+ fused p-weighted graph pooling)
    aggregate<<<N_NODES / 4, 256, 0, stream>>>(h1, src, row_ptr, inv_deg, aggb);
    gemm_fused<<<ggrid, 512, 0, stream>>>(aggb, h1, Wl2t, Wr2t, b2, h2, N_NODES, 0,
                                          p, batch, gsum, 1);

    // finale: root gather + gsum/cnt + final linear
    pool_final<<<N_GRAPHS, 128, 0, stream>>>(h2, graph_ptr, root_ptr, gsum,
                                             Wlin, blin, out);
}

// Round 7
// 314.992 us; speedup vs baseline: 1.1836x; 1.1836x over previous
//
#include <hip/hip_runtime.h>
#include <hip/hip_bf16.h>

// ---------- problem constants ----------
#define N_NODES 50000
#define N_EDGES 800000
#define C_DIM   256      // IN_C == HID_C
#define OUT_C   128
#define N_GRAPHS 256

typedef __bf16         bf16x8  __attribute__((ext_vector_type(8)));
typedef float          f32x4   __attribute__((ext_vector_type(4)));

typedef __attribute__((address_space(1))) const unsigned int gu32;
typedef __attribute__((address_space(3))) unsigned int lu32;

#if __has_builtin(__builtin_amdgcn_sched_barrier)
#define SCHED_FENCE() __builtin_amdgcn_sched_barrier(0)
#else
#define SCHED_FENCE() ((void)0)
#endif

__device__ __forceinline__ float us2f(unsigned short u) {
    unsigned int x = ((unsigned int)u) << 16;
    return __builtin_bit_cast(float, x);
}
__device__ __forceinline__ unsigned short f2bf(float f) {
    unsigned int u = __builtin_bit_cast(unsigned int, f);
    u += 0x7fffu + ((u >> 16) & 1u);   // RNE
    return (unsigned short)(u >> 16);
}

__device__ __forceinline__ int lower_bound_i(const int* __restrict__ a, int n, int v) {
    int lo = 0, hi = n;
    while (lo < hi) {
        int mid = (lo + hi) >> 1;
        if (a[mid] < v) lo = mid + 1; else hi = mid;
    }
    return lo;
}

// ---------- K1: merged preprocess (slim: 3385 blocks; verified R6, saved ~85 µs) ----------
// blocks [0,3125): convert x f32->bf16 (16 elems/thread, coalesced)
// blocks [3125,3189): LDS-tiled transpose+convert of the 4 weights
// blocks [3189,3385): CSR row_ptr/graph_ptr/inv_deg
__global__ void preprocess(const float* __restrict__ x, unsigned short* __restrict__ xb,
                           const float* __restrict__ W0, const float* __restrict__ W1,
                           const float* __restrict__ W2, const float* __restrict__ W3,
                           unsigned short* __restrict__ D0, unsigned short* __restrict__ D1,
                           unsigned short* __restrict__ D2, unsigned short* __restrict__ D3,
                           const int* __restrict__ dst, const int* __restrict__ batch,
                           int* __restrict__ row_ptr, int* __restrict__ graph_ptr,
                           float* __restrict__ inv_deg) {
    __shared__ float tile[64][65];
    int b = blockIdx.x;
    int t = threadIdx.x;
    if (b < 3125) {
        int base = b * 1024 + t;             // float4-group index
#pragma unroll
        for (int j = 0; j < 4; ++j) {
            int i = base + j * 256;          // < 3.2M
            float4 v = *(const float4*)(x + ((size_t)i << 2));
            ushort4 o;
            o.x = f2bf(v.x); o.y = f2bf(v.y); o.z = f2bf(v.z); o.w = f2bf(v.w);
            *(ushort4*)(xb + ((size_t)i << 2)) = o;
        }
    } else if (b < 3189) {
        int b2 = b - 3125;                   // 0..63: 4 matrices x 16 tiles
        const float* S; unsigned short* D;
        switch (b2 >> 4) {
            case 0: S = W0; D = D0; break;
            case 1: S = W1; D = D1; break;
            case 2: S = W2; D = D2; break;
            default: S = W3; D = D3; break;
        }
        int tl = b2 & 15;
        int kt = (tl >> 2) * 64, nt = (tl & 3) * 64;
#pragma unroll
        for (int j = 0; j < 16; ++j) {       // coalesced read of S[kt.., nt..]
            int idx = t + j * 256;
            int r = idx >> 6, c = idx & 63;
            tile[r][c] = S[(size_t)(kt + r) * 256 + nt + c];
        }
        __syncthreads();
#pragma unroll
        for (int j = 0; j < 16; ++j) {       // coalesced write of D[nt.., kt..]
            int idx = t + j * 256;
            int r = idx >> 6, c = idx & 63;
            D[(size_t)(nt + r) * 256 + kt + c] = f2bf(tile[c][r]);
        }
    } else {
        int i = (b - 3189) * 256 + t;
        if (i <= N_NODES) {
            int lb = lower_bound_i(dst, N_EDGES, i);
            row_ptr[i] = lb;
            if (i < N_NODES) {
                int ub = lower_bound_i(dst, N_EDGES, i + 1);
                int cnt = ub - lb;
                inv_deg[i] = (cnt > 0) ? (1.0f / (float)cnt) : 0.0f;
            }
        }
        if (i <= N_GRAPHS) graph_ptr[i] = lower_bound_i(batch, N_NODES, i);
    }
}

// ---------- K2: mean aggregation (round-0 verbatim — 57 µs structural ceiling) ----------
// One wave per node, scalar-base gathers, 16-deep fenced bursts. Do NOT fuse
// with GEMM (r1: −24%) or into a coop mega-kernel (r4: −3.5x).
__global__ void aggregate(const unsigned short* __restrict__ X,
                          const int* __restrict__ src,
                          const int* __restrict__ row_ptr,
                          const float* __restrict__ inv_deg,
                          unsigned short* __restrict__ out) {
    int gw   = (blockIdx.x * blockDim.x + threadIdx.x) >> 6;
    int lane = threadIdx.x & 63;
    if (gw >= N_NODES) return;
    int e0 = row_ptr[gw], e1 = row_ptr[gw + 1];
    const int lo = lane << 2;
    float a0 = 0.f, a1 = 0.f, a2 = 0.f, a3 = 0.f;
    int e = e0;

    for (; e + 16 <= e1; e += 16) {
        ushort4 v[16];
#pragma unroll
        for (int j = 0; j < 16; ++j) {
            int s = __builtin_amdgcn_readfirstlane(src[e + j]);
            v[j] = *(const ushort4*)(X + ((size_t)s << 8) + lo);
        }
        SCHED_FENCE();
#pragma unroll
        for (int j = 0; j < 16; ++j) {
            a0 += us2f(v[j].x); a1 += us2f(v[j].y);
            a2 += us2f(v[j].z); a3 += us2f(v[j].w);
        }
    }
    int rem = e1 - e;
    if (rem > 0) {
        int cl = e1 - 1;
        ushort4 v[16]; float w[16];
#pragma unroll
        for (int j = 0; j < 16; ++j) {
            int ej = e + j;
            int ec = ej < cl ? ej : cl;
            w[j] = (ej < e1) ? 1.0f : 0.0f;
            int s = __builtin_amdgcn_readfirstlane(src[ec]);
            v[j] = *(const ushort4*)(X + ((size_t)s << 8) + lo);
        }
        SCHED_FENCE();
#pragma unroll
        for (int j = 0; j < 16; ++j) {
            a0 = fmaf(us2f(v[j].x), w[j], a0);
            a1 = fmaf(us2f(v[j].y), w[j], a1);
            a2 = fmaf(us2f(v[j].z), w[j], a2);
            a3 = fmaf(us2f(v[j].w), w[j], a3);
        }
    }

    float sc = inv_deg[gw];
    ushort4 o;
    o.x = f2bf(a0 * sc); o.y = f2bf(a1 * sc); o.z = f2bf(a2 * sc); o.w = f2bf(a3 * sc);
    *(ushort4*)(out + ((size_t)gw << 8) + lo) = o;
}

// ---------- K3: fused SAGE GEMM (round-0 BYTE-IDENTICAL — isolation round) ----------
// 128-row strip x FULL N=256; 512 thr = 8 waves (2m x 4n), 4x4 MFMA 16x16x32
// per wave, BK=64. R6's pool-fused variant (+8KB LDS, extra args, reordered
// epilogue) ran 103 µs vs this shape's 32 µs — mechanism unidentified, so
// ALL deltas stripped. Do not modify this kernel without an A/B.
__global__ __launch_bounds__(512, 2)
void gemm_fused(const unsigned short* __restrict__ A1,
                const unsigned short* __restrict__ A2,
                const unsigned short* __restrict__ B1t,
                const unsigned short* __restrict__ B2t,
                const float* __restrict__ bias,
                unsigned short* __restrict__ C,
                int M, int do_relu) {
    __shared__ __align__(16) unsigned short As[8192];   // 128 rows x 8 chunks x 8
    __shared__ __align__(16) unsigned short Bs[16384];  // 256 rows x 8 chunks x 8

    const int t    = threadIdx.x;
    const int m0   = blockIdx.x * 128;
    const int lane = t & 63, wid = t >> 6;
    const int wm   = (wid >> 2) * 64;       // {0,64}
    const int wn   = (wid & 3) * 64;        // {0,64,128,192}
    const int lrow = lane & 15;
    const int kq   = lane >> 4;             // 0..3

    const f32x4 zero4 = {0.f, 0.f, 0.f, 0.f};
    f32x4 acc[4][4];
#pragma unroll
    for (int i = 0; i < 4; ++i)
#pragma unroll
        for (int j = 0; j < 4; ++j) acc[i][j] = zero4;

    for (int it = 0; it < 8; ++it) {        // K = 512 virtual (2 x 256), BK = 64
        const unsigned short* __restrict__ Ab = (it < 4) ? A1 : A2;
        const unsigned short* __restrict__ Bb = (it < 4) ? B1t : B2t;
        int ko = (it * 64) & 255;

#pragma unroll
        for (int i = 0; i < 2; ++i) {
            int q   = t + i * 512;          // 0..1023
            int row = q >> 3;
            int kb  = (q & 7) ^ (row & 7);
            const unsigned short* ga = Ab + (size_t)(m0 + row) * 256 + ko + kb * 8;
            __builtin_amdgcn_global_load_lds((gu32*)ga, (lu32*)(As + q * 8), 16, 0, 0);
        }
#pragma unroll
        for (int i = 0; i < 4; ++i) {
            int q   = t + i * 512;          // 0..2047
            int row = q >> 3;
            int kb  = (q & 7) ^ (row & 7);
            const unsigned short* gb = Bb + (size_t)row * 256 + ko + kb * 8;
            __builtin_amdgcn_global_load_lds((gu32*)gb, (lu32*)(Bs + q * 8), 16, 0, 0);
        }
        __syncthreads();

#pragma unroll
        for (int s = 0; s < 2; ++s) {       // two 32-k MFMA steps per BK=64
            int kqp = s * 4 + kq;
            bf16x8 af[4], bfr[4];
#pragma unroll
            for (int mi = 0; mi < 4; ++mi) {
                int r = wm + mi * 16 + lrow;
                int slot = r * 8 + (kqp ^ (lrow & 7));
                uint4 u = *(const uint4*)(As + slot * 8);
                af[mi] = __builtin_bit_cast(bf16x8, u);
            }
#pragma unroll
            for (int ni = 0; ni < 4; ++ni) {
                int r = wn + ni * 16 + lrow;
                int slot = r * 8 + (kqp ^ (lrow & 7));
                uint4 u = *(const uint4*)(Bs + slot * 8);
                bfr[ni] = __builtin_bit_cast(bf16x8, u);
            }
#pragma unroll
            for (int mi = 0; mi < 4; ++mi)
#pragma unroll
                for (int ni = 0; ni < 4; ++ni)
                    acc[mi][ni] = __builtin_amdgcn_mfma_f32_16x16x32_bf16(
                        af[mi], bfr[ni], acc[mi][ni], 0, 0, 0);
        }
        __syncthreads();
    }

    // epilogue: D mapping col = lane&15, row = (lane>>4)*4 + reg
    const int rbase = (lane >> 4) * 4;
#pragma unroll
    for (int ni = 0; ni < 4; ++ni) {
        int n  = wn + ni * 16 + lrow;
        float bv = bias[n];
#pragma unroll
        for (int mi = 0; mi < 4; ++mi) {
            int mb = m0 + wm + mi * 16 + rbase;
#pragma unroll
            for (int r = 0; r < 4; ++r) {
                int m = mb + r;
                if (m < M) {
                    float v = acc[mi][ni][r] + bv;
                    if (do_relu) v = fmaxf(v, 0.f);
                    C[(size_t)m * 256 + n] = f2bf(v);
                }
            }
        }
    }
}

// ---------- K4: fused pool + root gather + final linear (round-0 verbatim) ----------
__global__ void pool_final(const unsigned short* __restrict__ h2,
                           const float* __restrict__ p,
                           const int* __restrict__ graph_ptr,
                           const int* __restrict__ root_ptr,
                           const float* __restrict__ Wlin,
                           const float* __restrict__ blin,
                           float* __restrict__ out) {
    __shared__ float part[2][256];
    __shared__ float fl[512];
    int g = blockIdx.x;
    int t = threadIdx.x;        // 512 threads
    int c = t & 255;            // channel
    int half = t >> 8;          // 0 or 1
    int s = graph_ptr[g], e = graph_ptr[g + 1];
    int mid = s + ((e - s) >> 1);
    int lo0 = half ? mid : s;
    int hi0 = half ? e : mid;

    float acc = 0.f;
    for (int n = lo0; n < hi0; n += 8) {
        int cl = hi0 - 1;
        float w[8]; unsigned short v[8];
#pragma unroll
        for (int j = 0; j < 8; ++j) {
            int nj = n + j;
            int ncj = nj < cl ? nj : cl;
            int nu = __builtin_amdgcn_readfirstlane(ncj);
            w[j] = (nj < hi0) ? p[nu] : 0.0f;
            v[j] = h2[(size_t)nu * 256 + c];
        }
        SCHED_FENCE();
#pragma unroll
        for (int j = 0; j < 8; ++j)
            acc = fmaf(us2f(v[j]), w[j], acc);
    }
    part[half][c] = acc;
    __syncthreads();

    if (half == 0) {
        float cnt = (float)(e - s);
        int root = root_ptr[g];
        fl[c]       = us2f(h2[(size_t)root * 256 + c]);
        fl[256 + c] = (part[0][c] + part[1][c]) / fmaxf(cnt, 1.0f);
    }
    __syncthreads();

    if (t < 128) {
        int o = t;
        float s0 = 0.f, s1 = 0.f, s2 = 0.f, s3 = 0.f;
        for (int k = 0; k < 512; k += 4) {
            s0 = fmaf(fl[k + 0], Wlin[(k + 0) * 128 + o], s0);
            s1 = fmaf(fl[k + 1], Wlin[(k + 1) * 128 + o], s1);
            s2 = fmaf(fl[k + 2], Wlin[(k + 2) * 128 + o], s2);
            s3 = fmaf(fl[k + 3], Wlin[(k + 3) * 128 + o], s3);
        }
        out[(size_t)g * 128 + o] = blin[o] + ((s0 + s1) + (s2 + s3));
    }
}

extern "C" void kernel_launch(void* const* d_in, const int* in_sizes, int n_in,
                              void* d_out, int out_size, void* d_ws, size_t ws_size,
                              hipStream_t stream) {
    const float* x        = (const float*)d_in[0];
    const int*   src      = (const int*)d_in[1];
    const int*   dst      = (const int*)d_in[2];
    const float* p        = (const float*)d_in[3];
    const int*   batch    = (const int*)d_in[4];
    const int*   root_ptr = (const int*)d_in[5];
    // d_in[6] = num_graphs (256, hard-coded)
    const float* Wl1  = (const float*)d_in[7];
    const float* Wr1  = (const float*)d_in[8];
    const float* b1   = (const float*)d_in[9];
    const float* Wl2  = (const float*)d_in[10];
    const float* Wr2  = (const float*)d_in[11];
    const float* b2   = (const float*)d_in[12];
    const float* Wlin = (const float*)d_in[13];
    const float* blin = (const float*)d_in[14];
    float* out = (float*)d_out;

    // workspace layout (256B aligned slabs)
    size_t off = 0;
    char* base = (char*)d_ws;
    auto alloc = [&](size_t bytes) -> void* {
        void* q = base + off;
        off += (bytes + 255) & ~(size_t)255;
        return q;
    };
    int*            row_ptr   = (int*)  alloc((N_NODES + 1) * sizeof(int));
    int*            graph_ptr = (int*)  alloc((N_GRAPHS + 1) * sizeof(int));
    float*          inv_deg   = (float*)alloc(N_NODES * sizeof(float));
    unsigned short* Wl1t = (unsigned short*)alloc(256 * 256 * 2);
    unsigned short* Wr1t = (unsigned short*)alloc(256 * 256 * 2);
    unsigned short* Wl2t = (unsigned short*)alloc(256 * 256 * 2);
    unsigned short* Wr2t = (unsigned short*)alloc(256 * 256 * 2);
    unsigned short* xb   = (unsigned short*)alloc((size_t)N_NODES * 256 * 2);
    unsigned short* aggb = (unsigned short*)alloc((size_t)N_NODES * 256 * 2);
    unsigned short* h1   = (unsigned short*)alloc((size_t)N_NODES * 256 * 2);
    unsigned short* h2   = (unsigned short*)alloc((size_t)N_NODES * 256 * 2);
    (void)ws_size; (void)n_in; (void)in_sizes; (void)out_size;

    preprocess<<<3385, 256, 0, stream>>>(x, xb, Wl1, Wr1, Wl2, Wr2,
                                         Wl1t, Wr1t, Wl2t, Wr2t,
                                         dst, batch, row_ptr, graph_ptr, inv_deg);

    dim3 ggrid((N_NODES + 127) / 128);   // 391 blocks

    // conv1: h1 = relu(agg(x)@Wl1 + x@Wr1 + b1)
    aggregate<<<N_NODES / 4, 256, 0, stream>>>(xb, src, row_ptr, inv_deg, aggb);
    gemm_fused<<<ggrid, 512, 0, stream>>>(aggb, xb, Wl1t, Wr1t, b1, h1, N_NODES, 1);

    // conv2: h2 = agg(h1)@Wl2 + h1@Wr2 + b2
    aggregate<<<N_NODES / 4, 256, 0, stream>>>(h1, src, row_ptr, inv_deg, aggb);
    gemm_fused<<<ggrid, 512, 0, stream>>>(aggb, h1, Wl2t, Wr2t, b2, h2, N_NODES, 0);

    // fused pool + root gather + final linear
    pool_final<<<N_GRAPHS, 512, 0, stream>>>(h2, p, graph_ptr, root_ptr,
                                             Wlin, blin, out);
}